// Round 12
// baseline (238.230 us; speedup 1.0000x reference)
//
#include <hip/hip_runtime.h>
#include <hip/hip_bf16.h>

#define IN_F 8192
#define OUT_F 28672
#define RANK 32
#define NGROUPS 128          // IN_F / 64
#define M_TOK 16
#define TCHUNK 16            // K-chunks for lora-t partials
#define TCK (IN_F / TCHUNK)  // 512
#define NS 32                // block supersteps over K
#define SS 256               // k-elems (= ints) per row per superstep (1 KB)

typedef __bf16 bf16x8 __attribute__((ext_vector_type(8)));
typedef float  f32x4  __attribute__((ext_vector_type(4)));
typedef int    i32x4  __attribute__((ext_vector_type(4)));

#define GLOBAL_AS __attribute__((address_space(1)))
#define LDS_AS    __attribute__((address_space(3)))

// ---------------------------------------------------------------------------
// Kernel 1: lora-t partials + fused x f32->bf16 cast. 16 blocks x 512 thr.
// ---------------------------------------------------------------------------
__global__ __launch_bounds__(512) void svdq_prep(
    const float* __restrict__ x, const float* __restrict__ ld,
    float* __restrict__ part, __bf16* __restrict__ xb) {
  const int c = blockIdx.x;
  const int i = threadIdx.x;

  {
    const int base = c * 8192 + i * 16;
    f32x4 f0 = *reinterpret_cast<const f32x4*>(x + base);
    f32x4 f1 = *reinterpret_cast<const f32x4*>(x + base + 4);
    f32x4 f2 = *reinterpret_cast<const f32x4*>(x + base + 8);
    f32x4 f3 = *reinterpret_cast<const f32x4*>(x + base + 12);
    bf16x8 v0, v1;
#pragma unroll
    for (int j = 0; j < 4; ++j) {
      v0[j] = (__bf16)f0[j]; v0[j + 4] = (__bf16)f1[j];
      v1[j] = (__bf16)f2[j]; v1[j + 4] = (__bf16)f3[j];
    }
    *reinterpret_cast<bf16x8*>(xb + base)     = v0;
    *reinterpret_cast<bf16x8*>(xb + base + 8) = v1;
  }

  const int m = i >> 5, r = i & 31;
  const f32x4* xp = reinterpret_cast<const f32x4*>(x  + (size_t)m * IN_F + c * TCK);
  const f32x4* lp = reinterpret_cast<const f32x4*>(ld + (size_t)r * IN_F + c * TCK);
  float s = 0.f;
#pragma unroll 8
  for (int j = 0; j < TCK / 4; ++j) {
    f32x4 a = xp[j], b = lp[j];
    s += a[0]*b[0] + a[1]*b[1] + a[2]*b[2] + a[3]*b[3];
  }
  part[(size_t)c * (M_TOK * RANK) + i] = s;
}

// ---------------------------------------------------------------------------
// Kernel 2: fused dequant-GEMM + lora-up + bias, BLOCK-staged triple buffer.
// Identical to round 11 EXCEPT the prologue race fix: vmcnt(7)+s_barrier
// publishing superstep 0 to all waves BEFORE the first compute (round 11
// read other waves' buffer-0 rows with no barrier -> absmax 4.8e8).
// Loop protocol (verified by count): at iter t, vmcnt(7) leaves only this
// iter's X(t+1)+S(t+2) outstanding -> S(t+1) landed; s_barrier publishes it
// for iter t+1's compute. Triple buffer prevents stage-over-compute.
// grid = OUT_F/16 = 1792 blocks x 256 threads; 48 KB LDS -> 3 blocks/CU.
// ---------------------------------------------------------------------------
__global__ __launch_bounds__(256) void svdq_main(
    const __bf16* __restrict__ xb, const int* __restrict__ qw,
    const float* __restrict__ wsc, const float* __restrict__ lu,
    const float* __restrict__ bias, const float* __restrict__ part,
    float* __restrict__ out) {
  const int w     = threadIdx.x >> 6;
  const int lane  = threadIdx.x & 63;
  const int col   = lane & 15;
  const int hi    = lane >> 4;
  const int obase = blockIdx.x * 16;
  const int o     = obase + col;

  __shared__ int smem[3 * 4096];   // 48 KB: 3 buffers x 16 rows x 256 ints

  const int*    qb   = qw + (size_t)obase * IN_F;
  const __bf16* xrow = xb + (size_t)col * IN_F + hi * 8;
  const float*  srow = wsc + (size_t)o * NGROUPS;

  // Stage superstep T into buffer B: wave w loads rows w*4..w*4+3, each a
  // full 1 KB contiguous run (64 lanes x 16B, source chunk lane^(r&7)).
#define STAGE(T, B)                                                            \
  {                                                                            \
    _Pragma("unroll")                                                          \
    for (int j = 0; j < 4; ++j) {                                              \
      const int r = w * 4 + j;                                                 \
      const int* _s = qb + (size_t)r * IN_F + (T) * SS + ((lane ^ (r & 7)) << 2);\
      __builtin_amdgcn_global_load_lds((const GLOBAL_AS int*)_s,               \
          (LDS_AS int*)(smem + (B) * 4096 + r * 256), 16, 0, 0);               \
    }                                                                          \
  }

#define XLOAD(T, A0, A1, S)                                                    \
  {                                                                            \
    (A0) = *reinterpret_cast<const bf16x8*>(xrow + (T) * SS + w * 64);         \
    (A1) = *reinterpret_cast<const bf16x8*>(xrow + (T) * SS + w * 64 + 32);    \
    (S)  = srow[(T) * 4 + w];                                                  \
  }

  f32x4 acc = {0.f, 0.f, 0.f, 0.f};

  // Wave w computes k in [w*64, w*64+64) of buffer CB: chunks c0 = w*16+kk*8+hi*2.
#define COMPUTE(CB, A0, A1, S)                                                 \
  {                                                                            \
    const int* _base = smem + (CB) * 4096 + col * 256;                         \
    const int  _sw   = col & 7;                                                \
    _Pragma("unroll")                                                          \
    for (int kk = 0; kk < 2; ++kk) {                                           \
      const int c0 = w * 16 + kk * 8 + hi * 2;                                 \
      i32x4 q0 = *reinterpret_cast<const i32x4*>(_base + ((c0 ^ _sw) << 2));   \
      i32x4 q1 = *reinterpret_cast<const i32x4*>(_base + (((c0 + 1) ^ _sw) << 2));\
      bf16x8 b;                                                                \
      _Pragma("unroll")                                                        \
      for (int jj = 0; jj < 4; ++jj) {                                         \
        b[jj]     = (__bf16)((float)q0[jj] * (S));                             \
        b[jj + 4] = (__bf16)((float)q1[jj] * (S));                             \
      }                                                                        \
      acc = __builtin_amdgcn_mfma_f32_16x16x32_bf16(kk ? (A1) : (A0), b, acc,  \
                                                    0, 0, 0);                  \
    }                                                                          \
  }

  bf16x8 a0, a1, a0n, a1n;
  float  sc, scn;

  // Prologue (order pinned: S0 | X0 | S1). Then PUBLISH superstep 0:
  // vmcnt(7) leaves only S1(4)+X0(3) outstanding -> own S0 landed; barrier
  // -> ALL waves' S0 landed before iter-0 compute. (The round-11 bug.)
  STAGE(0, 0)
  asm volatile("" ::: "memory");
  XLOAD(0, a0, a1, sc)
  asm volatile("" ::: "memory");
  STAGE(1, 1)
  asm volatile("s_waitcnt vmcnt(7)" ::: "memory");
  __builtin_amdgcn_s_barrier();

  int cb = 0, sb = 2;
#pragma unroll 1
  for (int t = 0; t + 2 < NS; ++t) {
    XLOAD(t + 1, a0n, a1n, scn)                        // 3 vmem
    STAGE(t + 2, sb)                                   // 4 vmem
    asm volatile("s_waitcnt vmcnt(14)" ::: "memory");
    __builtin_amdgcn_sched_barrier(0);
    COMPUTE(cb, a0, a1, sc)
    asm volatile("s_waitcnt vmcnt(7)" ::: "memory");   // S(t+1) landed (own)
    __builtin_amdgcn_s_barrier();                      // publish S(t+1)
    a0 = a0n; a1 = a1n; sc = scn;
    cb = (cb == 2) ? 0 : cb + 1;
    sb = (sb == 2) ? 0 : sb + 1;
  }
  // t = NS-2 (no stage issued)
  XLOAD(NS - 1, a0n, a1n, scn)                         // 3 vmem
  asm volatile("s_waitcnt vmcnt(10)" ::: "memory");
  __builtin_amdgcn_sched_barrier(0);
  COMPUTE(cb, a0, a1, sc)
  asm volatile("s_waitcnt vmcnt(3)" ::: "memory");     // S(NS-1) landed (own)
  __builtin_amdgcn_s_barrier();                        // publish S(NS-1)
  a0 = a0n; a1 = a1n; sc = scn;
  cb = (cb == 2) ? 0 : cb + 1;
  // t = NS-1
  asm volatile("s_waitcnt vmcnt(0)" ::: "memory");
  __builtin_amdgcn_sched_barrier(0);
  COMPUTE(cb, a0, a1, sc)

#undef STAGE
#undef XLOAD
#undef COMPUTE

  // ---- split-K reduction: alias red[] onto (now dead) buffers ----
  __syncthreads();
  float* red = reinterpret_cast<float*>(smem);      // [4][64][4] = 4 KB
#pragma unroll
  for (int r = 0; r < 4; ++r) red[(w * 64 + lane) * 4 + r] = acc[r];
  __syncthreads();
  if (threadIdx.x >= 64) return;

  f32x4 tot = {0.f, 0.f, 0.f, 0.f};
#pragma unroll
  for (int ww = 0; ww < 4; ++ww)
    tot += *reinterpret_cast<const f32x4*>(red + (ww * 64 + lane) * 4);

  // ---- LoRA epilogue: reduce t partials, 1 MFMA, + bias ----
  f32x4 t0 = {0.f,0.f,0.f,0.f}, t1 = {0.f,0.f,0.f,0.f};
#pragma unroll
  for (int c = 0; c < TCHUNK; ++c) {
    const f32x4* pc = reinterpret_cast<const f32x4*>(
        part + (size_t)c * (M_TOK * RANK) + col * RANK + hi * 8);
    t0 += pc[0];
    t1 += pc[1];
  }
  f32x4 u0 = *reinterpret_cast<const f32x4*>(lu + (size_t)o * RANK + hi * 8);
  f32x4 u1 = *reinterpret_cast<const f32x4*>(lu + (size_t)o * RANK + hi * 8 + 4);
  bf16x8 ta, lb;
#pragma unroll
  for (int j = 0; j < 4; ++j) {
    ta[j]     = (__bf16)t0[j];
    ta[j + 4] = (__bf16)t1[j];
    lb[j]     = (__bf16)u0[j];
    lb[j + 4] = (__bf16)u1[j];
  }
  f32x4 lacc = {0.f, 0.f, 0.f, 0.f};
  lacc = __builtin_amdgcn_mfma_f32_16x16x32_bf16(ta, lb, lacc, 0, 0, 0);

  const float bv = bias[o];
#pragma unroll
  for (int reg = 0; reg < 4; ++reg) {
    const int m = hi * 4 + reg;
    out[(size_t)m * OUT_F + o] = tot[reg] + lacc[reg] + bv;
  }
}

extern "C" void kernel_launch(void* const* d_in, const int* in_sizes, int n_in,
                              void* d_out, int out_size, void* d_ws, size_t ws_size,
                              hipStream_t stream) {
  const float* x    = (const float*)d_in[0];
  const int*   qw   = (const int*)d_in[1];
  const float* wsc  = (const float*)d_in[2];
  const float* ld   = (const float*)d_in[3];
  const float* lu   = (const float*)d_in[4];
  const float* bias = (const float*)d_in[5];
  float*       out  = (float*)d_out;

  float*  part = (float*)d_ws;                          // 16*512 f32 = 32 KB
  __bf16* xbf  = (__bf16*)((char*)d_ws + 64 * 1024);    // 256 KB

  svdq_prep<<<TCHUNK, 512, 0, stream>>>(x, ld, part, xbf);
  svdq_main<<<OUT_F / 16, 256, 0, stream>>>(xbf, qw, wsc, lu, bias, part, out);
}

// Round 13
// 211.918 us; speedup vs baseline: 1.1242x; 1.1242x over previous
//
#include <hip/hip_runtime.h>
#include <hip/hip_bf16.h>

#define IN_F 8192
#define OUT_F 28672
#define RANK 32
#define NGROUPS 128          // IN_F / 64
#define M_TOK 16
#define TCHUNK 16            // K-chunks for lora-t partials
#define TCK (IN_F / TCHUNK)  // 512
#define NSTEP 64             // supersteps of 128 k over FULL K per wave

typedef __bf16 bf16x8 __attribute__((ext_vector_type(8)));
typedef float  f32x4  __attribute__((ext_vector_type(4)));
typedef int    i32x4  __attribute__((ext_vector_type(4)));

#define GLOBAL_AS __attribute__((address_space(1)))
#define LDS_AS    __attribute__((address_space(3)))

// ---------------------------------------------------------------------------
// Kernel 1: lora-t partials + fused x f32->bf16 cast. 16 blocks x 512 thr.
// ---------------------------------------------------------------------------
__global__ __launch_bounds__(512) void svdq_prep(
    const float* __restrict__ x, const float* __restrict__ ld,
    float* __restrict__ part, __bf16* __restrict__ xb) {
  const int c = blockIdx.x;
  const int i = threadIdx.x;

  {
    const int base = c * 8192 + i * 16;
    f32x4 f0 = *reinterpret_cast<const f32x4*>(x + base);
    f32x4 f1 = *reinterpret_cast<const f32x4*>(x + base + 4);
    f32x4 f2 = *reinterpret_cast<const f32x4*>(x + base + 8);
    f32x4 f3 = *reinterpret_cast<const f32x4*>(x + base + 12);
    bf16x8 v0, v1;
#pragma unroll
    for (int j = 0; j < 4; ++j) {
      v0[j] = (__bf16)f0[j]; v0[j + 4] = (__bf16)f1[j];
      v1[j] = (__bf16)f2[j]; v1[j + 4] = (__bf16)f3[j];
    }
    *reinterpret_cast<bf16x8*>(xb + base)     = v0;
    *reinterpret_cast<bf16x8*>(xb + base + 8) = v1;
  }

  const int m = i >> 5, r = i & 31;
  const f32x4* xp = reinterpret_cast<const f32x4*>(x  + (size_t)m * IN_F + c * TCK);
  const f32x4* lp = reinterpret_cast<const f32x4*>(ld + (size_t)r * IN_F + c * TCK);
  float s = 0.f;
#pragma unroll 8
  for (int j = 0; j < TCK / 4; ++j) {
    f32x4 a = xp[j], b = lp[j];
    s += a[0]*b[0] + a[1]*b[1] + a[2]*b[2] + a[3]*b[3];
  }
  part[(size_t)c * (M_TOK * RANK) + i] = s;
}

// ---------------------------------------------------------------------------
// Kernel 2: fused dequant-GEMM + lora-up + bias.
// 448 blocks x 256 thr = 1792 waves, ALL co-resident (LDS 64 KB -> 2/CU,
// 448 <= 512 slots). Each wave: one 16-col tile x FULL K, fully independent
// (no split-K, no barriers, wave-private double-buffered staging).
// R9-proven pipeline: supersteps of 128 k, rows staged 2/instr at 512 B
// contiguous runs, source XOR swizzle (chunk l32^(row&7)), counted vmcnt(13)
// = 4 x-loads + 1 scale + 8 stages per iteration window.
// Removes R9's grid-quantization loss (1792 blocks / 512 slots = 3.5 -> 4
// sequential rounds, +14%): all blocks stream concurrently, finish together.
// ---------------------------------------------------------------------------
__global__ __launch_bounds__(256) void svdq_main(
    const __bf16* __restrict__ xb, const int* __restrict__ qw,
    const float* __restrict__ wsc, const float* __restrict__ lu,
    const float* __restrict__ bias, const float* __restrict__ part,
    float* __restrict__ out) {
  const int w     = threadIdx.x >> 6;
  const int lane  = threadIdx.x & 63;
  const int col   = lane & 15;
  const int hi    = lane >> 4;
  const int l32   = lane & 31;
  const int rhalf = lane >> 5;
  const int obase = blockIdx.x * 64 + w * 16;   // wave-private 16-col tile
  const int o     = obase + col;

  __shared__ int smem[4 * 4096];   // 64 KB; wave w owns [w*4096, +4096) ints
  int* mybuf = smem + w * 4096;    // 2 buffers x 2048 ints (8 KB each)

  const int*    qbase = qw + (size_t)(obase + rhalf) * IN_F;
  const __bf16* xrow  = xb + (size_t)col * IN_F + hi * 8;
  const float*  srow  = wsc + (size_t)o * NGROUPS;

  // per-lane swizzled source offsets (ints) for rows (2j + rhalf): period 4
  int xoff[4];
#pragma unroll
  for (int j = 0; j < 4; ++j) xoff[j] = (l32 ^ ((2 * j + rhalf) & 7)) * 4;

  // Stage superstep T (128 k per row, 16 rows = 8 KB) into buffer B.
  // Instr i: rows 2i+rhalf, 512 B contiguous each (lane's 16B chunk at
  // source chunk l32^(row&7)); LDS dest linear -> row r at mybuf+B*2048+r*128.
#define STAGE(T, B)                                                            \
  {                                                                            \
    _Pragma("unroll")                                                          \
    for (int i = 0; i < 8; ++i) {                                              \
      const int* _s = qbase + (size_t)(2 * i) * IN_F + (T) * 128 + xoff[i & 3];\
      __builtin_amdgcn_global_load_lds((const GLOBAL_AS int*)_s,               \
          (LDS_AS int*)(mybuf + (B) * 2048 + i * 256), 16, 0, 0);              \
    }                                                                          \
  }

  f32x4 acc = {0.f, 0.f, 0.f, 0.f};

  // kk=0..3: lane reads row col, source chunks c0 = kk*8+hi*2, c0+1
  // (stored at slot c ^ (col&7)).
#define COMPUTE(B, A0, A1, A2, A3, SC)                                         \
  {                                                                            \
    const int* _base = mybuf + (B) * 2048 + col * 128;                         \
    const int  _sw   = col & 7;                                                \
    _Pragma("unroll")                                                          \
    for (int kk = 0; kk < 4; ++kk) {                                           \
      const int c0 = kk * 8 + hi * 2;                                          \
      i32x4 q0 = *reinterpret_cast<const i32x4*>(_base + ((c0 ^ _sw) * 4));    \
      i32x4 q1 = *reinterpret_cast<const i32x4*>(_base + (((c0 + 1) ^ _sw) * 4));\
      const float s = (kk < 2) ? (SC).x : (SC).y;                              \
      bf16x8 b;                                                                \
      _Pragma("unroll")                                                        \
      for (int j = 0; j < 4; ++j) {                                            \
        b[j]     = (__bf16)((float)q0[j] * s);                                 \
        b[j + 4] = (__bf16)((float)q1[j] * s);                                 \
      }                                                                        \
      bf16x8 _a = (kk == 0) ? (A0) : (kk == 1) ? (A1) : (kk == 2) ? (A2) : (A3);\
      acc = __builtin_amdgcn_mfma_f32_16x16x32_bf16(_a, b, acc, 0, 0, 0);      \
    }                                                                          \
  }

  // Prologue: stage superstep 0; prefetch x/scales for superstep 0.
  STAGE(0, 0)
  bf16x8 a0 = *reinterpret_cast<const bf16x8*>(xrow);
  bf16x8 a1 = *reinterpret_cast<const bf16x8*>(xrow + 32);
  bf16x8 a2 = *reinterpret_cast<const bf16x8*>(xrow + 64);
  bf16x8 a3 = *reinterpret_cast<const bf16x8*>(xrow + 96);
  float2 sc = *reinterpret_cast<const float2*>(srow);

#pragma unroll 1
  for (int t = 0; t < NSTEP - 1; ++t) {
    // window: 4 x-loads + 1 scale + 8 stages = 13 vmem for superstep t+1
    const __bf16* xn = xrow + (t + 1) * 128;
    bf16x8 n0 = *reinterpret_cast<const bf16x8*>(xn);
    bf16x8 n1 = *reinterpret_cast<const bf16x8*>(xn + 32);
    bf16x8 n2 = *reinterpret_cast<const bf16x8*>(xn + 64);
    bf16x8 n3 = *reinterpret_cast<const bf16x8*>(xn + 96);
    float2 sn = *reinterpret_cast<const float2*>(srow + (t + 1) * 2);
    STAGE(t + 1, (t + 1) & 1)
    asm volatile("s_waitcnt vmcnt(13)" ::: "memory");  // superstep t landed
    __builtin_amdgcn_sched_barrier(0);
    COMPUTE(t & 1, a0, a1, a2, a3, sc)
    a0 = n0; a1 = n1; a2 = n2; a3 = n3; sc = sn;
  }
  asm volatile("s_waitcnt vmcnt(0)" ::: "memory");
  __builtin_amdgcn_sched_barrier(0);
  COMPUTE((NSTEP - 1) & 1, a0, a1, a2, a3, sc)

#undef STAGE
#undef COMPUTE

  // ---- epilogue (wave-private; acc already holds the full-K sum) ----
  f32x4 t0 = {0.f,0.f,0.f,0.f}, t1 = {0.f,0.f,0.f,0.f};
#pragma unroll
  for (int c = 0; c < TCHUNK; ++c) {
    const f32x4* pc = reinterpret_cast<const f32x4*>(
        part + (size_t)c * (M_TOK * RANK) + col * RANK + hi * 8);
    t0 += pc[0];
    t1 += pc[1];
  }
  f32x4 u0 = *reinterpret_cast<const f32x4*>(lu + (size_t)o * RANK + hi * 8);
  f32x4 u1 = *reinterpret_cast<const f32x4*>(lu + (size_t)o * RANK + hi * 8 + 4);
  bf16x8 ta, lb;
#pragma unroll
  for (int j = 0; j < 4; ++j) {
    ta[j]     = (__bf16)t0[j];
    ta[j + 4] = (__bf16)t1[j];
    lb[j]     = (__bf16)u0[j];
    lb[j + 4] = (__bf16)u1[j];
  }
  f32x4 lacc = {0.f, 0.f, 0.f, 0.f};
  lacc = __builtin_amdgcn_mfma_f32_16x16x32_bf16(ta, lb, lacc, 0, 0, 0);

  const float bv = bias[o];
#pragma unroll
  for (int reg = 0; reg < 4; ++reg) {
    const int m = hi * 4 + reg;
    out[(size_t)m * OUT_F + o] = acc[reg] + lacc[reg] + bv;
  }
}

extern "C" void kernel_launch(void* const* d_in, const int* in_sizes, int n_in,
                              void* d_out, int out_size, void* d_ws, size_t ws_size,
                              hipStream_t stream) {
  const float* x    = (const float*)d_in[0];
  const int*   qw   = (const int*)d_in[1];
  const float* wsc  = (const float*)d_in[2];
  const float* ld   = (const float*)d_in[3];
  const float* lu   = (const float*)d_in[4];
  const float* bias = (const float*)d_in[5];
  float*       out  = (float*)d_out;

  float*  part = (float*)d_ws;                          // 16*512 f32 = 32 KB
  __bf16* xbf  = (__bf16*)((char*)d_ws + 64 * 1024);    // 256 KB

  svdq_prep<<<TCHUNK, 512, 0, stream>>>(x, ld, part, xbf);
  svdq_main<<<OUT_F / 64, 256, 0, stream>>>(xbf, qw, wsc, lu, bias, part, out);
}